// Round 1
// baseline (46.725 us; speedup 1.0000x reference)
//
#include <hip/hip_runtime.h>

#define C 32
#define H 192
#define W 192
#define HW (H*W)        // 36864
#define NPIX (HW*2)     // 73728 flat columns (h,w,n)

// K1: z[o, p] = sum_c conv_w[o,c] * x[c, p]   (1x1 mix first; commutes with pixconv)
__global__ __launch_bounds__(256) void k1_mix(
    const float* __restrict__ x, const float* __restrict__ cw, float* __restrict__ z)
{
    const int p = blockIdx.x * 256 + threadIdx.x;   // grid sized exactly
    float xv[C];
#pragma unroll
    for (int c = 0; c < C; ++c) xv[c] = x[c * NPIX + p];
    const float4* cw4 = reinterpret_cast<const float4*>(cw);
#pragma unroll
    for (int o = 0; o < C; ++o) {
        float acc = 0.f;
#pragma unroll
        for (int q = 0; q < 8; ++q) {
            const float4 wv = cw4[o * 8 + q];
            acc += wv.x * xv[q*4+0];
            acc += wv.y * xv[q*4+1];
            acc += wv.z * xv[q*4+2];
            acc += wv.w * xv[q*4+3];
        }
        z[o * NPIX + p] = acc;
    }
}

// K2: out[o,h,w,n] = sum_{i,j} w1[i*7+j, h, w] * z[o, h+i-3, w+j-3, n] + cb[o]
// thread = (h, wg of 4 w-pixels, og of 4 o-channels), both n via float2-packed layout.
__global__ __launch_bounds__(192) void k2_pix(
    const float* __restrict__ z, const float* __restrict__ w1,
    const float* __restrict__ cb, float* __restrict__ out)
{
    const int h   = blockIdx.x;
    const int tid = threadIdx.x;
    const int wg  = tid % 48;                    // w-group: pixels w0..w0+3
    const int og  = blockIdx.y * 4 + tid / 48;   // o-group: channels ob..ob+3
    const int w0  = wg * 4;
    const int ob  = og * 4;

    float acc[4][8];                             // [oo][wp*2 + n]
#pragma unroll
    for (int a = 0; a < 4; ++a)
#pragma unroll
        for (int b = 0; b < 8; ++b) acc[a][b] = 0.f;

#pragma unroll
    for (int i = 0; i < 7; ++i) {
        const int yy = h + i - 3;
        if (yy < 0 || yy >= H) continue;         // uniform per wave (h is per-block)

        // per-pixel weights for output row h, cols w0..w0+3, tap row i
        float4 wt[7];
#pragma unroll
        for (int j = 0; j < 7; ++j)
            wt[j] = *reinterpret_cast<const float4*>(&w1[((i*7+j)*H + h)*W + w0]);

#pragma unroll
        for (int oo = 0; oo < 4; ++oo) {
            const float* zrow = z + ((size_t)(ob + oo) * H + yy) * (W * 2);
            // 12-wide (w0-4 .. w0+7) x 2n register window = 24 floats, 6 aligned float4
            float zf[24];
            float4* zv = reinterpret_cast<float4*>(zf);
            if (wg > 0) {
                zv[0] = *reinterpret_cast<const float4*>(&zrow[(w0-4)*2]);
                zv[1] = *reinterpret_cast<const float4*>(&zrow[(w0-4)*2 + 4]);
            } else {
                zv[0] = make_float4(0.f,0.f,0.f,0.f);
                zv[1] = make_float4(0.f,0.f,0.f,0.f);
            }
            zv[2] = *reinterpret_cast<const float4*>(&zrow[w0*2]);
            zv[3] = *reinterpret_cast<const float4*>(&zrow[w0*2 + 4]);
            if (wg < 47) {
                zv[4] = *reinterpret_cast<const float4*>(&zrow[(w0+4)*2]);
                zv[5] = *reinterpret_cast<const float4*>(&zrow[(w0+4)*2 + 4]);
            } else {
                zv[4] = make_float4(0.f,0.f,0.f,0.f);
                zv[5] = make_float4(0.f,0.f,0.f,0.f);
            }
#pragma unroll
            for (int j = 0; j < 7; ++j) {
                const float wj[4] = { wt[j].x, wt[j].y, wt[j].z, wt[j].w };
#pragma unroll
                for (int wp = 0; wp < 4; ++wp) {
                    const int q = 2 * (wp + j + 1);   // col w0+wp+j-3 -> window idx
                    acc[oo][wp*2+0] += wj[wp] * zf[q];
                    acc[oo][wp*2+1] += wj[wp] * zf[q+1];
                }
            }
        }
    }

    // epilogue: + bias, store 8 contiguous floats (4 w-pixels x 2 n) per channel
#pragma unroll
    for (int oo = 0; oo < 4; ++oo) {
        const float bv = cb[ob + oo];
        float r[8];
#pragma unroll
        for (int b = 0; b < 8; ++b) r[b] = acc[oo][b] + bv;
        float* orow = out + ((size_t)(ob + oo) * H + h) * (W * 2) + w0 * 2;
        *reinterpret_cast<float4*>(&orow[0]) = *reinterpret_cast<const float4*>(&r[0]);
        *reinterpret_cast<float4*>(&orow[4]) = *reinterpret_cast<const float4*>(&r[4]);
    }
}

extern "C" void kernel_launch(void* const* d_in, const int* in_sizes, int n_in,
                              void* d_out, int out_size, void* d_ws, size_t ws_size,
                              hipStream_t stream) {
    const float* x  = (const float*)d_in[0];   // (C,H,W,2)
    const float* w1 = (const float*)d_in[1];   // (1,1,49,H,W)
    const float* cw = (const float*)d_in[2];   // (C_out, C_in)
    const float* cb = (const float*)d_in[3];   // (C,)
    float* z   = (float*)d_ws;                 // (C,H,W,2) mixed intermediate, 9.44 MB
    float* out = (float*)d_out;                // (C,H,W,2)

    hipLaunchKernelGGL(k1_mix, dim3(NPIX/256), dim3(256), 0, stream, x, cw, z);
    hipLaunchKernelGGL(k2_pix, dim3(H, 2), dim3(192), 0, stream, z, w1, cb, out);
}

// Round 2
// 34.723 us; speedup vs baseline: 1.3456x; 1.3456x over previous
//
#include <hip/hip_runtime.h>

#define C 32
#define H 192
#define W 192
#define HW (H*W)        // 36864
#define NPIX (HW*2)     // 73728 flat columns (h,w,n)
#define KK 7
#define TAPS 49

// K1: z[o, p] = sum_c conv_w[o,c] * x[c, p]   (1x1 mix first; commutes with pixconv)
// o split into halves across grid.y for occupancy (9 waves/CU vs 4.5).
__global__ __launch_bounds__(256) void k1_mix(
    const float* __restrict__ x, const float* __restrict__ cw, float* __restrict__ z)
{
    const int p  = blockIdx.x * 256 + threadIdx.x;
    const int ob = blockIdx.y * 16;
    float xv[C];
#pragma unroll
    for (int c = 0; c < C; ++c) xv[c] = x[c * NPIX + p];
    const float4* cw4 = reinterpret_cast<const float4*>(cw);
#pragma unroll
    for (int oo = 0; oo < 16; ++oo) {
        const int o = ob + oo;
        float acc = 0.f;
#pragma unroll
        for (int q = 0; q < 8; ++q) {
            const float4 wv = cw4[o * 8 + q];
            acc += wv.x * xv[q*4+0];
            acc += wv.y * xv[q*4+1];
            acc += wv.z * xv[q*4+2];
            acc += wv.w * xv[q*4+3];
        }
        z[o * NPIX + p] = acc;
    }
}

// K2: out[o,h,w,n] = sum_{i,j} w1[i*7+j, h, w] * z[o, h+i-3, w+j-3, n] + cb[o]
// Block: one output row h, 8 o-channels (2 per thread), 192 threads (wg 0..47 x og 0..3).
// Row weights (49x192 = 36.75 KB) staged in LDS once, shared across all o in block.
__global__ __launch_bounds__(192) void k2_pix(
    const float* __restrict__ z, const float* __restrict__ w1,
    const float* __restrict__ cb, float* __restrict__ out)
{
    __shared__ float wlds[TAPS * W];             // 36.75 KB -> 3 blocks/CU fits 160 KB

    const int h   = blockIdx.x;
    const int tid = threadIdx.x;
    const int wg  = tid % 48;                    // w-group: pixels w0..w0+3
    const int og  = tid / 48;                    // 0..3
    const int w0  = wg * 4;
    const int ob  = blockIdx.y * 8 + og * 2;     // 2 channels per thread

    // --- cooperative stage of row-h per-pixel weights: wlds[t*W + w] = w1[t,h,w]
    {
        const int wq = tid % 48;                 // float4 column
        const int t0 = tid / 48;                 // 0..3
#pragma unroll
        for (int k = 0; k < 12; ++k) {
            const int t = k * 4 + t0;            // taps 0..47
            const float4 v = *reinterpret_cast<const float4*>(&w1[((size_t)t * H + h) * W + wq * 4]);
            *reinterpret_cast<float4*>(&wlds[t * W + wq * 4]) = v;
        }
        // tap 48 tail: 192 floats, one scalar each
        wlds[48 * W + tid] = w1[((size_t)48 * H + h) * W + tid];
    }
    __syncthreads();

    float acc[2][8];                             // [oo][wp*2 + n]
#pragma unroll
    for (int a = 0; a < 2; ++a)
#pragma unroll
        for (int b = 0; b < 8; ++b) acc[a][b] = 0.f;

#pragma unroll
    for (int i = 0; i < KK; ++i) {
        const int yy = h + i - 3;
        if (yy < 0 || yy >= H) continue;         // uniform per block

        float4 wt[KK];
#pragma unroll
        for (int j = 0; j < KK; ++j)
            wt[j] = *reinterpret_cast<const float4*>(&wlds[(i * KK + j) * W + w0]);

#pragma unroll
        for (int oo = 0; oo < 2; ++oo) {
            const float* zrow = z + ((size_t)(ob + oo) * H + yy) * (W * 2);
            // 12-wide (w0-4 .. w0+7) x 2n register window = 24 floats, 6 aligned float4
            float zf[24];
            float4* zv = reinterpret_cast<float4*>(zf);
            if (wg > 0) {
                zv[0] = *reinterpret_cast<const float4*>(&zrow[(w0-4)*2]);
                zv[1] = *reinterpret_cast<const float4*>(&zrow[(w0-4)*2 + 4]);
            } else {
                zv[0] = make_float4(0.f,0.f,0.f,0.f);
                zv[1] = make_float4(0.f,0.f,0.f,0.f);
            }
            zv[2] = *reinterpret_cast<const float4*>(&zrow[w0*2]);
            zv[3] = *reinterpret_cast<const float4*>(&zrow[w0*2 + 4]);
            if (wg < 47) {
                zv[4] = *reinterpret_cast<const float4*>(&zrow[(w0+4)*2]);
                zv[5] = *reinterpret_cast<const float4*>(&zrow[(w0+4)*2 + 4]);
            } else {
                zv[4] = make_float4(0.f,0.f,0.f,0.f);
                zv[5] = make_float4(0.f,0.f,0.f,0.f);
            }
#pragma unroll
            for (int j = 0; j < KK; ++j) {
                const float wj[4] = { wt[j].x, wt[j].y, wt[j].z, wt[j].w };
#pragma unroll
                for (int wp = 0; wp < 4; ++wp) {
                    const int q = 2 * (wp + j + 1);   // col w0+wp+j-3 -> window idx
                    acc[oo][wp*2+0] += wj[wp] * zf[q];
                    acc[oo][wp*2+1] += wj[wp] * zf[q+1];
                }
            }
        }
    }

    // epilogue: + bias, store 8 contiguous floats (4 w-pixels x 2 n) per channel
#pragma unroll
    for (int oo = 0; oo < 2; ++oo) {
        const float bv = cb[ob + oo];
        float r[8];
#pragma unroll
        for (int b = 0; b < 8; ++b) r[b] = acc[oo][b] + bv;
        float* orow = out + ((size_t)(ob + oo) * H + h) * (W * 2) + w0 * 2;
        *reinterpret_cast<float4*>(&orow[0]) = *reinterpret_cast<const float4*>(&r[0]);
        *reinterpret_cast<float4*>(&orow[4]) = *reinterpret_cast<const float4*>(&r[4]);
    }
}

extern "C" void kernel_launch(void* const* d_in, const int* in_sizes, int n_in,
                              void* d_out, int out_size, void* d_ws, size_t ws_size,
                              hipStream_t stream) {
    const float* x  = (const float*)d_in[0];   // (C,H,W,2)
    const float* w1 = (const float*)d_in[1];   // (1,1,49,H,W)
    const float* cw = (const float*)d_in[2];   // (C_out, C_in)
    const float* cb = (const float*)d_in[3];   // (C,)
    float* z   = (float*)d_ws;                 // (C,H,W,2) mixed intermediate, 9.44 MB
    float* out = (float*)d_out;                // (C,H,W,2)

    hipLaunchKernelGGL(k1_mix, dim3(NPIX/256, 2), dim3(256), 0, stream, x, cw, z);
    hipLaunchKernelGGL(k2_pix, dim3(H, 4), dim3(192), 0, stream, z, w1, cb, out);
}

// Round 3
// 30.092 us; speedup vs baseline: 1.5527x; 1.1539x over previous
//
#include <hip/hip_runtime.h>

#define C 32
#define H 192
#define W 192
#define HW (H*W)        // 36864
#define NPIX (HW*2)     // 73728
#define KK 7
#define WPB 16          // output pixels per (single-wave) block in k2
#define NWB (W/WPB)     // 12 blocks per row
#define K2_BLOCKS (NWB*H)   // 2304
#define K2_CPX (K2_BLOCKS/8) // 288 blocks per XCD chunk

// K1: z[hw][o*2+n] = sum_c cw[o,c] * x[c][hw][n]   (TRANSPOSED z: channel innermost)
// thread = one hw pixel (both n), 8 o-channels; grid.y = 4 covers o.
__global__ __launch_bounds__(256) void k1_mix(
    const float* __restrict__ x, const float* __restrict__ cw, float* __restrict__ z)
{
    const int hw = blockIdx.x * 256 + threadIdx.x;
    const int ob = blockIdx.y * 8;

    const float2* x2 = reinterpret_cast<const float2*>(x);
    float2 xv[C];
#pragma unroll
    for (int c = 0; c < C; ++c) xv[c] = x2[(size_t)c * HW + hw];

    float acc[8][2];
#pragma unroll
    for (int oo = 0; oo < 8; ++oo) { acc[oo][0] = 0.f; acc[oo][1] = 0.f; }

#pragma unroll
    for (int c = 0; c < C; ++c) {
#pragma unroll
        for (int oo = 0; oo < 8; ++oo) {
            const float wc = cw[(ob + oo) * C + c];   // uniform -> s_load
            acc[oo][0] += wc * xv[c].x;
            acc[oo][1] += wc * xv[c].y;
        }
    }

    // 16 consecutive floats at z[hw*64 + 2*ob]  (full 64B sector, aligned)
    float* zp = z + (size_t)hw * 64 + ob * 2;
#pragma unroll
    for (int q = 0; q < 4; ++q) {
        float4 r = make_float4(acc[2*q][0], acc[2*q][1], acc[2*q+1][0], acc[2*q+1][1]);
        *reinterpret_cast<float4*>(zp + 4 * q) = r;
    }
}

// K2: out[o][h][w][n] = sum_{i,j} w1[i*7+j,h,w] * z[(h+i-3)*W + (w+j-3)][o*2+n] + cb[o]
// Single-wave block: lane = o*2+n, 16 output pixels of row h.
// Weights are wave-uniform (h, w0 from blockIdx) -> scalar loads, SGPR FMA operands.
__global__ __launch_bounds__(64) void k2_conv(
    const float* __restrict__ z, const float* __restrict__ w1,
    const float* __restrict__ cb, float* __restrict__ out)
{
    __shared__ float tr[WPB * 66];               // epilogue transpose, padded

    const int b  = blockIdx.x;
    const int l  = (b & 7) * K2_CPX + (b >> 3);  // XCD-contiguous h chunks (bijective)
    const int wb = l % NWB;
    const int h  = l / NWB;
    const int w0 = wb * WPB;
    const int lane = threadIdx.x;                // o*2+n

    float acc[WPB];
#pragma unroll
    for (int p = 0; p < WPB; ++p) acc[p] = 0.f;

#pragma unroll
    for (int i = 0; i < KK; ++i) {
        const int yy = h + i - 3;
        if (yy < 0 || yy >= H) continue;         // uniform

        // window cols w0-3 .. w0+18, coalesced 256B per column load
        float zw[WPB + 6];
        const float* zrow = z + (size_t)yy * (W * 64) + lane;
#pragma unroll
        for (int k = 0; k < WPB + 6; ++k) {
            const int cc = w0 - 3 + k;
            zw[k] = (cc >= 0 && cc < W) ? zrow[(size_t)cc * 64] : 0.f;  // uniform predicate
        }

#pragma unroll
        for (int j = 0; j < KK; ++j) {
            const float* wrow = w1 + ((size_t)(i * KK + j)) * HW + h * W + w0; // uniform
            const float4 wa = *reinterpret_cast<const float4*>(wrow + 0);
            const float4 wb4 = *reinterpret_cast<const float4*>(wrow + 4);
            const float4 wc4 = *reinterpret_cast<const float4*>(wrow + 8);
            const float4 wd4 = *reinterpret_cast<const float4*>(wrow + 12);
            const float wt[WPB] = { wa.x, wa.y, wa.z, wa.w, wb4.x, wb4.y, wb4.z, wb4.w,
                                    wc4.x, wc4.y, wc4.z, wc4.w, wd4.x, wd4.y, wd4.z, wd4.w };
#pragma unroll
            for (int px = 0; px < WPB; ++px)
                acc[px] += wt[px] * zw[px + j];
        }
    }

    // epilogue: add bias, regroup via LDS so stores are 16B chunks per lane
    const float bias = cb[lane >> 1];
#pragma unroll
    for (int px = 0; px < WPB; ++px)
        tr[px * 66 + lane] = acc[px] + bias;
    __syncthreads();                             // single wave; cheap ordering

    // lane -> (o = lane>>1, half = lane&1): 16 floats = 8 px x 2 n, contiguous in out
    {
        const int o    = lane >> 1;
        const int half = lane & 1;
        float* obase = out + (size_t)o * NPIX + ((size_t)h * W + w0 + half * 8) * 2;
#pragma unroll
        for (int m = 0; m < 4; ++m) {
            float4 r;
            r.x = tr[(half * 8 + 2*m    ) * 66 + (o << 1) + 0];
            r.y = tr[(half * 8 + 2*m    ) * 66 + (o << 1) + 1];
            r.z = tr[(half * 8 + 2*m + 1) * 66 + (o << 1) + 0];
            r.w = tr[(half * 8 + 2*m + 1) * 66 + (o << 1) + 1];
            *reinterpret_cast<float4*>(obase + 4 * m) = r;
        }
    }
}

extern "C" void kernel_launch(void* const* d_in, const int* in_sizes, int n_in,
                              void* d_out, int out_size, void* d_ws, size_t ws_size,
                              hipStream_t stream) {
    const float* x  = (const float*)d_in[0];   // (C,H,W,2)
    const float* w1 = (const float*)d_in[1];   // (1,1,49,H,W)
    const float* cw = (const float*)d_in[2];   // (C_out, C_in)
    const float* cb = (const float*)d_in[3];   // (C,)
    float* z   = (float*)d_ws;                 // (HW, 64) transposed mix, 9.44 MB
    float* out = (float*)d_out;                // (C,H,W,2)

    hipLaunchKernelGGL(k1_mix, dim3(HW / 256, 4), dim3(256), 0, stream, x, cw, z);
    hipLaunchKernelGGL(k2_conv, dim3(K2_BLOCKS), dim3(64), 0, stream, z, w1, cb, out);
}

// Round 4
// 25.509 us; speedup vs baseline: 1.8317x; 1.1797x over previous
//
#include <hip/hip_runtime.h>

#define C 32
#define H 192
#define W 192
#define HW (H*W)        // 36864
#define NPIX (HW*2)     // 73728
#define KK 7
#define TAPS 49

// ---------------- K1: z[hw][o*2+n] = sum_c cw[o,c] * x[c][hw][n] ----------------
// 1D grid 576 = 8 XCD chunks of 72 = (18 hw-blocks x 4 o-passes); XCD-local x reuse.
__global__ __launch_bounds__(256) void k1_mix(
    const float* __restrict__ x, const float* __restrict__ cw, float* __restrict__ z)
{
    __shared__ float wl[256];                    // cw slice: [c][oo] = cw[ob+oo][c]
    const int b  = blockIdx.x;
    const int l  = (b & 7) * 72 + (b >> 3);      // bijective XCD swizzle (576%8==0)
    const int hwblk = l >> 2;
    const int ob    = (l & 3) * 8;
    const int tid   = threadIdx.x;

    wl[tid] = cw[(ob + (tid & 7)) * C + (tid >> 3)];   // wl[c*8+oo]
    __syncthreads();

    const int hw = hwblk * 256 + tid;
    const float2* x2 = reinterpret_cast<const float2*>(x);
    float2 xv[C];
#pragma unroll
    for (int c = 0; c < C; ++c) xv[c] = x2[(size_t)c * HW + hw];

    float acc[8][2];
#pragma unroll
    for (int oo = 0; oo < 8; ++oo) { acc[oo][0] = 0.f; acc[oo][1] = 0.f; }

#pragma unroll
    for (int c = 0; c < C; ++c) {
        const float4 wa = *reinterpret_cast<const float4*>(&wl[c * 8]);     // uniform -> broadcast
        const float4 wb = *reinterpret_cast<const float4*>(&wl[c * 8 + 4]);
        const float wt[8] = { wa.x, wa.y, wa.z, wa.w, wb.x, wb.y, wb.z, wb.w };
#pragma unroll
        for (int oo = 0; oo < 8; ++oo) {
            acc[oo][0] += wt[oo] * xv[c].x;
            acc[oo][1] += wt[oo] * xv[c].y;
        }
    }

    float* zp = z + (size_t)hw * 64 + ob * 2;
#pragma unroll
    for (int q = 0; q < 4; ++q) {
        float4 r = make_float4(acc[2*q][0], acc[2*q][1], acc[2*q+1][0], acc[2*q+1][1]);
        *reinterpret_cast<float4*>(zp + 4 * q) = r;
    }
}

// ---------------- K2: pixelwise 7x7 over transposed z ----------------
// Block = 256 thr = 4 waves; wave = 8 output px of row h, lane = o*2+n.
// Per-pixel weights staged in LDS (uniform ds_read_b128 broadcast, off the VMEM pipe).
#define K2_BLOCKS 1152   // 192 rows x 6 wq
__global__ __launch_bounds__(256) void k2_conv(
    const float* __restrict__ z, const float* __restrict__ w1,
    const float* __restrict__ cb, float* __restrict__ out)
{
    __shared__ float wl[TAPS * 32];              // [t][32 px]   6.27 KB
    __shared__ float tr[4][8 * 66];              // per-wave epilogue transpose 8.45 KB

    const int b  = blockIdx.x;
    const int l  = (b & 7) * (K2_BLOCKS / 8) + (b >> 3);  // XCD row-band swizzle
    const int h  = l / 6;
    const int wq = l % 6;
    const int tid  = threadIdx.x;
    const int wv   = tid >> 6;
    const int lane = tid & 63;                   // o*2+n
    const int w0   = wq * 32 + wv * 8;           // this wave's first output col

    // stage w1[t][h][wq*32 .. +32) for all 49 taps
#pragma unroll
    for (int k = 0; k < 7; ++k) {
        const int v = k * 256 + tid;
        if (v < TAPS * 32) {
            const int t = v >> 5, c = v & 31;
            wl[v] = w1[(size_t)t * HW + h * W + wq * 32 + c];
        }
    }
    __syncthreads();

    float acc[8];
#pragma unroll
    for (int p = 0; p < 8; ++p) acc[p] = 0.f;

#pragma unroll
    for (int i = 0; i < KK; ++i) {
        const int yy = h + i - 3;
        if (yy < 0 || yy >= H) continue;         // uniform per block

        // z window cols w0-3 .. w0+10 (14), coalesced 256B per load, clamp+select for edges
        float zw[14];
        const float* zr = z + (size_t)yy * (W * 64) + lane;
#pragma unroll
        for (int k = 0; k < 14; ++k) {
            const int cc  = w0 - 3 + k;                       // uniform
            const int ccc = cc < 0 ? 0 : (cc > W - 1 ? W - 1 : cc);
            const float v = zr[ccc * 64];                     // always in-bounds
            zw[k] = (cc == ccc) ? v : 0.f;
        }

#pragma unroll
        for (int j = 0; j < KK; ++j) {
            const float4 wa = *reinterpret_cast<const float4*>(&wl[(i*KK + j) * 32 + wv * 8]);
            const float4 wb4 = *reinterpret_cast<const float4*>(&wl[(i*KK + j) * 32 + wv * 8 + 4]);
            acc[0] += wa.x  * zw[j + 0];
            acc[1] += wa.y  * zw[j + 1];
            acc[2] += wa.z  * zw[j + 2];
            acc[3] += wa.w  * zw[j + 3];
            acc[4] += wb4.x * zw[j + 4];
            acc[5] += wb4.y * zw[j + 5];
            acc[6] += wb4.z * zw[j + 6];
            acc[7] += wb4.w * zw[j + 7];
        }
    }

    // epilogue: bias + per-wave LDS transpose -> 16B stores
    const float bias = cb[lane >> 1];
    float* trw = &tr[wv][0];
#pragma unroll
    for (int p = 0; p < 8; ++p) trw[p * 66 + lane] = acc[p] + bias;
    __syncthreads();

    const int o = lane >> 1, half = lane & 1;
    float v8[8];
#pragma unroll
    for (int m = 0; m < 8; ++m) {
        const int f = half * 8 + m;              // float index in o's 16-float run
        v8[m] = trw[(f >> 1) * 66 + o * 2 + (f & 1)];
    }
    float* obase = out + (size_t)o * NPIX + ((size_t)h * W + w0) * 2 + half * 8;
    *reinterpret_cast<float4*>(obase)     = make_float4(v8[0], v8[1], v8[2], v8[3]);
    *reinterpret_cast<float4*>(obase + 4) = make_float4(v8[4], v8[5], v8[6], v8[7]);
}

extern "C" void kernel_launch(void* const* d_in, const int* in_sizes, int n_in,
                              void* d_out, int out_size, void* d_ws, size_t ws_size,
                              hipStream_t stream) {
    const float* x  = (const float*)d_in[0];   // (C,H,W,2)
    const float* w1 = (const float*)d_in[1];   // (1,1,49,H,W)
    const float* cw = (const float*)d_in[2];   // (C_out, C_in)
    const float* cb = (const float*)d_in[3];   // (C,)
    float* z   = (float*)d_ws;                 // (HW, 64) transposed mix
    float* out = (float*)d_out;                // (C,H,W,2)

    hipLaunchKernelGGL(k1_mix, dim3(576), dim3(256), 0, stream, x, cw, z);
    hipLaunchKernelGGL(k2_conv, dim3(K2_BLOCKS), dim3(256), 0, stream, z, w1, cb, out);
}